// Round 14
// baseline (632.338 us; speedup 1.0000x reference)
//
#include <hip/hip_runtime.h>

typedef unsigned short u16;
typedef __attribute__((ext_vector_type(8))) short s16x8;
typedef __attribute__((ext_vector_type(4))) float f32x4;

#define R3 32768
#define NPTS 16384

__device__ __forceinline__ float b2f(u16 u) {
  union { unsigned int i; float f; } v; v.i = ((unsigned int)u) << 16; return v.f;
}
__device__ __forceinline__ u16 f2b(float f) {
  union { float f; unsigned int i; } v; v.f = f;
  unsigned int x = v.i;
  return (u16)((x + 0x7fffu + ((x >> 16) & 1u)) >> 16);
}
__device__ __forceinline__ void split2(float x, u16& h, u16& l) {
  h = f2b(x); l = f2b(x - b2f(h));
}
__device__ __forceinline__ float silu(float x) {
  return x / (1.f + __expf(-x));
}

// ---- K0: weights -> hi/lo bf16. conv: [tap][co][ci]; mlp: [co][ci] --------
__global__ void convert_weights(const float* __restrict__ w1, const float* __restrict__ w2,
                                const float* __restrict__ wm,
                                u16* __restrict__ Wh1, u16* __restrict__ Wl1,
                                u16* __restrict__ Wh2, u16* __restrict__ Wl2,
                                u16* __restrict__ Whm, u16* __restrict__ Wlm) {
  int e = blockIdx.x * 256 + threadIdx.x;
  if (e < 27 * 128 * 64) {
    int t = e / (128 * 64), co = (e / 64) % 128, ci = e % 64;
    split2(w1[(co * 64 + ci) * 27 + t], Wh1[e], Wl1[e]);
  }
  if (e < 27 * 128 * 128) {
    int t = e / (128 * 128), co = (e / 128) % 128, ci = e % 128;
    split2(w2[(co * 128 + ci) * 27 + t], Wh2[e], Wl2[e]);
  }
  if (e < 128 * 64) split2(wm[e], Whm[e], Wlm[e]);
}

// ---- K_scatter_mlp: fused scatter + mlp MFMA (PROVEN r13) -----------------
__global__ void __launch_bounds__(256)
scatter_mlp(const float* __restrict__ coords, const float* __restrict__ features,
            const u16* __restrict__ Whm, const u16* __restrict__ Wlm,
            const float* __restrict__ mb,
            float* __restrict__ Gsum, float* __restrict__ Gcnt,
            u16* __restrict__ pf, float* __restrict__ stats) {
  constexpr int TRB = 64 * 65 * 4;          // 16640 B fp32 trans
  constexpr int XSB = 64 * 72 * 2;          // 9216 B bf16 Xs
  constexpr int SBYTES = 4 * 64 * 33 * 4;   // 33792 B epilogue scratch
  constexpr int LBYTES = (TRB + XSB > SBYTES) ? TRB + XSB : SBYTES;
  __shared__ __align__(16) char ldsbuf[LBYTES];
  float (*trans)[65] = (float(*)[65])ldsbuf;
  u16* Xs = (u16*)(ldsbuf + TRB);
  float* ldsW = (float*)ldsbuf;             // aliases; valid after barrier
  __shared__ int vox[64];

  const int tid = threadIdx.x;
  const int wave = tid >> 6, lane = tid & 63;
  const int l15 = lane & 15, q = lane >> 4;
  const int cobase = wave * 32;
  const int bi = blockIdx.x >> 8;
  const int n0 = (blockIdx.x & 255) << 6;

  // calibration (PROVEN r8)
  u16 oneb = f2b(1.0f), lidb = f2b((float)(l15 + 1));
  s16x8 vone, vlid;
#pragma unroll
  for (int e = 0; e < 8; ++e) { vone[e] = (short)oneb; vlid[e] = (short)lidb; }
  f32x4 z4 = {0.f, 0.f, 0.f, 0.f};
  f32x4 d1 = __builtin_amdgcn_mfma_f32_16x16x32_bf16(vlid, vone, z4, 0, 0, 0);
  f32x4 d2 = __builtin_amdgcn_mfma_f32_16x16x32_bf16(vone, vlid, z4, 0, 0, 0);
  int mdec[4], ndec[4];
#pragma unroll
  for (int r = 0; r < 4; ++r) {
    mdec[r] = (int)(d1[r] * 0.03125f + 0.5f) - 1;
    ndec[r] = (int)(d2[r] * 0.03125f + 0.5f) - 1;
  }

  if (tid < 64) {
    const float* cp = coords + ((size_t)bi * NPTS + n0 + tid) * 3;
    int ix = min(max((int)floorf(cp[0] * 32.f), 0), 31);
    int iy = min(max((int)floorf(cp[1] * 32.f), 0), 31);
    int iz = min(max((int)floorf(cp[2] * 32.f), 0), 31);
    vox[tid] = (ix * 32 + iy) * 32 + iz;
  }
  // dual-write staging: one global read feeds both views
  for (int e = tid; e < 4096; e += 256) {
    int ci = e >> 6, nn = e & 63;          // lane varies nn -> coalesced read
    float f = features[((size_t)bi * 64 + ci) * NPTS + n0 + nn];
    trans[nn][ci] = f;
    Xs[nn * 72 + ci] = f2b(f);
  }
  __syncthreads();

  // ---- scatter atomics first (fire-and-forget; drain under MFMA) ----------
  for (int pi = 0; pi < 16; ++pi) {
    int nn = wave * 16 + pi;
    int v = vox[nn];
    atomicAdd(&Gsum[((size_t)bi * R3 + v) * 64 + lane], trans[nn][lane]);
    if (lane == 0) atomicAdd(&Gcnt[bi * R3 + v], 1.f);
  }

  // ---- mlp MFMA (verbatim from proven mlp_mfma) ---------------------------
  f32x4 acc[2][4];  // [ct][vt: 4 point-tiles of 16]
#pragma unroll
  for (int a = 0; a < 2; ++a)
#pragma unroll
    for (int b = 0; b < 4; ++b) acc[a][b] = (f32x4){0.f, 0.f, 0.f, 0.f};

#pragma unroll
  for (int kb = 0; kb < 2; ++kb) {
    const int ko = kb * 32 + q * 8;
    s16x8 ah[2], al[2], bb[4];
#pragma unroll
    for (int ct = 0; ct < 2; ++ct) {
      size_t wo = ((size_t)(cobase + ct * 16 + l15)) * 64 + ko;
      ah[ct] = *(const s16x8*)(Whm + wo);
      al[ct] = *(const s16x8*)(Wlm + wo);
    }
#pragma unroll
    for (int vt = 0; vt < 4; ++vt)
      bb[vt] = *(const s16x8*)(&Xs[(vt * 16 + l15) * 72 + ko]);
#pragma unroll
    for (int ct = 0; ct < 2; ++ct)
#pragma unroll
      for (int vt = 0; vt < 4; ++vt) {
        acc[ct][vt] = __builtin_amdgcn_mfma_f32_16x16x32_bf16(ah[ct], bb[vt], acc[ct][vt], 0, 0, 0);
        acc[ct][vt] = __builtin_amdgcn_mfma_f32_16x16x32_bf16(al[ct], bb[vt], acc[ct][vt], 0, 0, 0);
      }
  }

  // epilogue: decoded scatter -> ldsW[wave][pt][co32], then store + stats
  __syncthreads();   // all trans/Xs reads done -> ldsW may overwrite
#pragma unroll
  for (int ct = 0; ct < 2; ++ct)
#pragma unroll
    for (int vt = 0; vt < 4; ++vt)
#pragma unroll
      for (int r = 0; r < 4; ++r)
        ldsW[(wave * 64 + vt * 16 + ndec[r]) * 33 + ct * 16 + mdec[r]] = acc[ct][vt][r];
  __syncthreads();

  float v[32];
  float s0 = 0.f, q0 = 0.f, s1 = 0.f, q1 = 0.f;
#pragma unroll
  for (int j = 0; j < 32; ++j) {
    v[j] = ldsW[(wave * 64 + lane) * 33 + j] + mb[cobase + j];
    if (j < 16) { s0 += v[j]; q0 = fmaf(v[j], v[j], q0); }
    else        { s1 += v[j]; q1 = fmaf(v[j], v[j], q1); }
  }
  u16 outv[32];
#pragma unroll
  for (int j = 0; j < 32; ++j) outv[j] = f2b(v[j]);
  u16* yp = pf + ((size_t)bi * NPTS + n0 + lane) * 128 + cobase;
#pragma unroll
  for (int k = 0; k < 4; ++k) *(uint4*)(yp + 8 * k) = *(uint4*)(outv + 8 * k);

#pragma unroll
  for (int off = 32; off > 0; off >>= 1) {
    s0 += __shfl_xor(s0, off); q0 += __shfl_xor(q0, off);
    s1 += __shfl_xor(s1, off); q1 += __shfl_xor(q1, off);
  }
  if (lane == 0) {
    atomicAdd(&stats[(bi * 8 + 2 * wave + 0) * 2 + 0], s0);
    atomicAdd(&stats[(bi * 8 + 2 * wave + 0) * 2 + 1], q0);
    atomicAdd(&stats[(bi * 8 + 2 * wave + 1) * 2 + 0], s1);
    atomicAdd(&stats[(bi * 8 + 2 * wave + 1) * 2 + 1], q1);
  }
}

// ---- conv: 3-phase slab staging (r8-proven, 262 us) -----------------------
// GSRC=true (conv1): staging reads Gsum/Gcnt directly and applies the
// EXACT finalize math f2b(s / fmaxf(c,1)) per element -- bit-identical to
// the old standalone finalize_grid (deterministic, same inputs), so the
// separate kernel + X1 buffer are eliminated. GSRC=false (conv2): bf16 X.
// Conv structure CLOSED (r1-r4, r6-r7, r9-r12: MfmaUtil pinned 34-38%
// across occupancy 12-44%, LDS ratio x0.5-x2, both MFMA shapes, three
// staging schemes, all prefetch variants). Do not reopen.
// 2-term split MFMA + calibrated C/D decode (PROVEN r8/r9).
template<int CIN, bool GSRC>
__global__ void __launch_bounds__(256)
conv_mfma_s3(const u16* __restrict__ X, const float* __restrict__ Gsrc,
             const float* __restrict__ Gcntp,
             const u16* __restrict__ Wh, const u16* __restrict__ Wl,
             const float* __restrict__ bias, const float* __restrict__ gamma,
             const float* __restrict__ beta, u16* __restrict__ Yb) {
  constexpr int CINP = CIN + 8;            // row stride (odd x 16B)
  constexpr int ROWS = 204;                // 6 y-lines x 34 z (jy=0..5, pz=0..33)
  constexpr int CH8 = CIN / 8;
  constexpr int KS = CIN / 32;
  constexpr int NCH = ROWS * CH8;          // 1632 / 3264 chunks per slab
  constexpr int XBYTES = ROWS * CINP * 2;  // 29376 / 55488
  constexpr int SBYTES = 4 * 2 * 32 * 33 * 4;   // 4 waves x 2 lines x [32co][33z]
  __shared__ __align__(16) char ldsbuf[(XBYTES > SBYTES) ? XBYTES : SBYTES];
  u16* Xs = (u16*)ldsbuf;
  float* ldsW = (float*)ldsbuf;            // valid only after X reads drained

  const int tid = threadIdx.x;
  const int wave = tid >> 6, lane = tid & 63;
  const int l15 = lane & 15, q = lane >> 4;
  const int cobase = wave * 32;

  const int bi = blockIdx.x >> 8;
  const int rem = blockIdx.x & 255;
  const int x = rem >> 3, y0 = (rem & 7) << 2;

  // ---- runtime C/D calibration (PROVEN r8) ----
  u16 oneb = f2b(1.0f), lidb = f2b((float)(l15 + 1));
  s16x8 vone, vlid;
#pragma unroll
  for (int e = 0; e < 8; ++e) { vone[e] = (short)oneb; vlid[e] = (short)lidb; }
  f32x4 z4 = {0.f, 0.f, 0.f, 0.f};
  f32x4 d1 = __builtin_amdgcn_mfma_f32_16x16x32_bf16(vlid, vone, z4, 0, 0, 0);
  f32x4 d2 = __builtin_amdgcn_mfma_f32_16x16x32_bf16(vone, vlid, z4, 0, 0, 0);
  int mdec[4], ndec[4];
#pragma unroll
  for (int r = 0; r < 4; ++r) {
    mdec[r] = (int)(d1[r] * 0.03125f + 0.5f) - 1;
    ndec[r] = (int)(d2[r] * 0.03125f + 0.5f) - 1;
  }

  f32x4 acc[2][2][4];  // [ct][vt][line]
#pragma unroll
  for (int a = 0; a < 2; ++a)
#pragma unroll
    for (int b = 0; b < 2; ++b)
#pragma unroll
      for (int c = 0; c < 4; ++c) acc[a][b][c] = (f32x4){0.f, 0.f, 0.f, 0.f};

  for (int dxs = 0; dxs < 3; ++dxs) {
    __syncthreads();
    const int xs = x + dxs - 1;
    for (int c = tid; c < NCH; c += 256) {   // bounds-checked staging
      int rr = c / CH8, k = (c % CH8) * 8;
      uint4 val; val.x = val.y = val.z = val.w = 0u;
      int jy = rr / 34;                    // 0..5
      int pz = rr - jy * 34;               // 0..33
      int ys = y0 + jy - 1, zz = pz - 1;
      if (xs >= 0 && xs < 32 && ys >= 0 && ys < 32 && zz >= 0 && zz < 32) {
        size_t vbase = (size_t)bi * R3 + (size_t)((xs * 32 + ys) * 32 + zz);
        if (GSRC) {
          float cgc = fmaxf(Gcntp[vbase], 1.f);
          const float4* gp = (const float4*)(Gsrc + vbase * CIN + k);
          float4 a = gp[0], b = gp[1];
          u16 o[8];
          o[0] = f2b(a.x / cgc); o[1] = f2b(a.y / cgc);
          o[2] = f2b(a.z / cgc); o[3] = f2b(a.w / cgc);
          o[4] = f2b(b.x / cgc); o[5] = f2b(b.y / cgc);
          o[6] = f2b(b.z / cgc); o[7] = f2b(b.w / cgc);
          val = *(const uint4*)o;
        } else {
          val = *(const uint4*)(X + vbase * CIN + k);
        }
      }
      *(uint4*)(&Xs[rr * CINP + k]) = val;
    }
    __syncthreads();
    for (int dy = 0; dy < 3; ++dy) {       // runtime loop: r0-sized inner body
      const int tb = dxs * 9 + dy * 3;
      const int rbase = dy * 34;
#pragma unroll
      for (int dz = 0; dz < 3; ++dz) {
        const int t = tb + dz;
#pragma unroll
        for (int kb = 0; kb < KS; ++kb) {
          const int ko = kb * 32 + q * 8;
          s16x8 ah[2], al[2], bb[2][4];
#pragma unroll
          for (int ct = 0; ct < 2; ++ct) {
            size_t wo = ((size_t)(t * 128 + cobase + ct * 16 + l15)) * CIN + ko;
            ah[ct] = *(const s16x8*)(Wh + wo);
            al[ct] = *(const s16x8*)(Wl + wo);
          }
#pragma unroll
          for (int vt = 0; vt < 2; ++vt)
#pragma unroll
            for (int ln = 0; ln < 4; ++ln)
              bb[vt][ln] = *(const s16x8*)(
                  &Xs[(rbase + ln * 34 + vt * 16 + l15 + dz) * CINP + ko]);
#pragma unroll
          for (int ct = 0; ct < 2; ++ct)
#pragma unroll
            for (int vt = 0; vt < 2; ++vt)
#pragma unroll
              for (int ln = 0; ln < 4; ++ln) {
                acc[ct][vt][ln] = __builtin_amdgcn_mfma_f32_16x16x32_bf16(
                    ah[ct], bb[vt][ln], acc[ct][vt][ln], 0, 0, 0);
                acc[ct][vt][ln] = __builtin_amdgcn_mfma_f32_16x16x32_bf16(
                    al[ct], bb[vt][ln], acc[ct][vt][ln], 0, 0, 0);
              }
        }
      }
    }
  }

  // ---- epilogue: decoded scatter through LDS, 2 lines per pass (r0) -------
  const int half = lane >> 5, zl = lane & 31;
  for (int p = 0; p < 2; ++p) {
    __syncthreads();   // drains Xs reads -> safe to overwrite
#pragma unroll
    for (int l2 = 0; l2 < 2; ++l2)
#pragma unroll
      for (int ct = 0; ct < 2; ++ct)
#pragma unroll
        for (int vt = 0; vt < 2; ++vt)
#pragma unroll
          for (int r = 0; r < 4; ++r)
            ldsW[((wave * 2 + l2) * 32 + ct * 16 + mdec[r]) * 33 + vt * 16 + ndec[r]] =
                acc[ct][vt][2 * p + l2][r];
    __syncthreads();
    const int co0 = cobase + half * 16;
#pragma unroll
    for (int l2 = 0; l2 < 2; ++l2) {
      float v[16];
#pragma unroll
      for (int j = 0; j < 16; ++j)
        v[j] = ldsW[((wave * 2 + l2) * 32 + half * 16 + j) * 33 + zl] + bias[co0 + j];
      float mu = 0.f;
#pragma unroll
      for (int j = 0; j < 16; ++j) mu += v[j];
      mu *= 0.0625f;
      float var = 0.f;
#pragma unroll
      for (int j = 0; j < 16; ++j) { float d = v[j] - mu; var = fmaf(d, d, var); }
      var *= 0.0625f;
      float rs = rsqrtf(var + 1e-5f);
#pragma unroll
      for (int j = 0; j < 16; ++j) {
        float xn = (v[j] - mu) * rs * gamma[co0 + j] + beta[co0 + j];
        v[j] = silu(xn);
      }
      size_t row = (size_t)bi * R3 + (size_t)((x * 32 + y0 + 2 * p + l2) * 32 + zl);
      u16 outv[16];
#pragma unroll
      for (int j = 0; j < 16; ++j) outv[j] = f2b(v[j]);
      u16* yp = Yb + row * 128 + co0;
      *(uint4*)(yp)     = *(uint4*)(outv);
      *(uint4*)(yp + 8) = *(uint4*)(outv + 8);
    }
  }
}

// ---- K_final (proven) -----------------------------------------------------
__global__ void __launch_bounds__(256)
final_fuse(const float* __restrict__ coords, const u16* __restrict__ H,
           const u16* __restrict__ pf, const float* __restrict__ stats,
           const float* __restrict__ gg, const float* __restrict__ gb,
           float* __restrict__ out) {
  __shared__ float trans[64][130];
  const int tid = threadIdx.x;
  const int wave = tid >> 6, lane = tid & 63;
  const int bi = blockIdx.x >> 8;
  const int p0 = (blockIdx.x & 255) << 6;
  const int co = lane * 2;
  const int grp = co >> 4;
  const float cntInv = 1.f / (16.f * 16384.f);
  float S  = stats[(bi * 8 + grp) * 2 + 0];
  float SS = stats[(bi * 8 + grp) * 2 + 1];
  float mu = S * cntInv;
  float var = SS * cntInv - mu * mu;
  float rs = rsqrtf(var + 1e-5f);
  float g0 = gg[co], g1 = gg[co + 1], b0 = gb[co], b1 = gb[co + 1];

  for (int pi = 0; pi < 16; ++pi) {
    int pl = wave * 16 + pi;
    int p = p0 + pl;
    const float* cp = coords + ((size_t)bi * NPTS + p) * 3;
    float cx = cp[0] * 32.f, cy = cp[1] * 32.f, cz = cp[2] * 32.f;
    float fx = floorf(cx), fy = floorf(cy), fz = floorf(cz);
    int ix = min(max((int)fx, 0), 31);
    int iy = min(max((int)fy, 0), 31);
    int iz = min(max((int)fz, 0), 31);
    float rx = cx - fx, ry = cy - fy, rz = cz - fz;
    int hx = min(ix + 1, 31), hy = min(iy + 1, 31), hz = min(iz + 1, 31);
    float a0 = 0.f, a1 = 0.f;
#pragma unroll
    for (int k = 0; k < 8; ++k) {
      int xb = k >> 2, yb = (k >> 1) & 1, zb = k & 1;
      float w = (xb ? rx : 1.f - rx) * (yb ? ry : 1.f - ry) * (zb ? rz : 1.f - rz);
      int vi = ((xb ? hx : ix) * 32 + (yb ? hy : iy)) * 32 + (zb ? hz : iz);
      unsigned hv = *(const unsigned*)(H + ((size_t)bi * R3 + vi) * 128 + co);
      a0 += w * b2f((u16)(hv & 0xffff));
      a1 += w * b2f((u16)(hv >> 16));
    }
    unsigned pv = *(const unsigned*)(pf + ((size_t)bi * NPTS + p) * 128 + co);
    float q0 = (b2f((u16)(pv & 0xffff)) - mu) * rs * g0 + b0;
    float q1 = (b2f((u16)(pv >> 16)) - mu) * rs * g1 + b1;
    trans[pl][co]     = silu(q0) + a0;
    trans[pl][co + 1] = silu(q1) + a1;
  }
  __syncthreads();
  for (int e = tid; e < 8192; e += 256) {
    int c = e >> 6, pp = e & 63;
    out[((size_t)bi * 128 + c) * NPTS + p0 + pp] = trans[pp][c];
  }
}

// ---- host -----------------------------------------------------------------
extern "C" void kernel_launch(void* const* d_in, const int* in_sizes, int n_in,
                              void* d_out, int out_size, void* d_ws, size_t ws_size,
                              hipStream_t stream) {
  const float* coords   = (const float*)d_in[0];
  const float* features = (const float*)d_in[1];
  const float* conv1_w  = (const float*)d_in[2];
  const float* conv1_b  = (const float*)d_in[3];
  const float* gn1_g    = (const float*)d_in[4];
  const float* gn1_b    = (const float*)d_in[5];
  const float* conv2_w  = (const float*)d_in[6];
  const float* conv2_b  = (const float*)d_in[7];
  const float* gn2_g    = (const float*)d_in[8];
  const float* gn2_b    = (const float*)d_in[9];
  const float* mlp_w    = (const float*)d_in[10];
  const float* mlp_b    = (const float*)d_in[11];
  const float* gnp_g    = (const float*)d_in[12];
  const float* gnp_b    = (const float*)d_in[13];

  char* ws = (char*)d_ws;
  // layout (bytes) -- compact layout; X1 eliminated (conv1 reads Gsum):
  float* Gsum = (float*)(ws + 0);            // 33554432 fp32 [b][vox][64]; H bf16 aliases after conv1
  u16*   H    = (u16*)(ws + 0);              // 33554432 bf16 [b][vox][128]
  u16*   X2   = (u16*)(ws + 50331648);       // 33554432 bf16 [b][vox][128] -> 83886080
  float* Gcnt = (float*)(ws + 83886080);     // 524288   -> 84410368
  float* stats = (float*)(ws + 84410368);    // 4096     -> 84414464
  u16*   pf   = (u16*)(ws + 84676608);       // 16777216 -> 101453824
  u16*   Wh1  = (u16*)(ws + 101453824);      // 442368   -> 101896192
  u16*   Wl1  = (u16*)(ws + 101896192);      // 442368   -> 102338560
  u16*   Wh2  = (u16*)(ws + 102338560);      // 884736   -> 103223296
  u16*   Wl2  = (u16*)(ws + 103223296);      // 884736   -> 104108032
  u16*   Whm  = (u16*)(ws + 104108032);      // 16384    -> 104124416
  u16*   Wlm  = (u16*)(ws + 104124416);      // 16384    -> 104140800 (~104 MB)

  hipMemsetAsync(ws, 0, 33554432, stream);                   // Gsum
  hipMemsetAsync(ws + 83886080, 0, 524288 + 4096, stream);   // Gcnt + stats

  convert_weights<<<(27 * 128 * 128 + 255) / 256, 256, 0, stream>>>(
      conv1_w, conv2_w, mlp_w, Wh1, Wl1, Wh2, Wl2, Whm, Wlm);
  scatter_mlp<<<1024, 256, 0, stream>>>(coords, features, Whm, Wlm, mlp_b,
                                        Gsum, Gcnt, pf, stats);
  conv_mfma_s3<64, true><<<1024, 256, 0, stream>>>(
      nullptr, Gsum, Gcnt, Wh1, Wl1, conv1_b, gn1_g, gn1_b, X2);
  conv_mfma_s3<128, false><<<1024, 256, 0, stream>>>(
      X2, nullptr, nullptr, Wh2, Wl2, conv2_b, gn2_g, gn2_b, H);
  final_fuse<<<1024, 256, 0, stream>>>(coords, H, pf, stats, gnp_g, gnp_b,
                                       (float*)d_out);
}

// Round 15
// 623.412 us; speedup vs baseline: 1.0143x; 1.0143x over previous
//
#include <hip/hip_runtime.h>

typedef unsigned short u16;
typedef __attribute__((ext_vector_type(8))) short s16x8;
typedef __attribute__((ext_vector_type(4))) float f32x4;

#define R3 32768
#define NPTS 16384

__device__ __forceinline__ float b2f(u16 u) {
  union { unsigned int i; float f; } v; v.i = ((unsigned int)u) << 16; return v.f;
}
__device__ __forceinline__ u16 f2b(float f) {
  union { float f; unsigned int i; } v; v.f = f;
  unsigned int x = v.i;
  return (u16)((x + 0x7fffu + ((x >> 16) & 1u)) >> 16);
}
__device__ __forceinline__ void split2(float x, u16& h, u16& l) {
  h = f2b(x); l = f2b(x - b2f(h));
}
__device__ __forceinline__ float silu(float x) {
  return x / (1.f + __expf(-x));
}

// ---- K0: weights -> hi/lo bf16. conv: [tap][co][ci]; mlp: [co][ci] --------
__global__ void convert_weights(const float* __restrict__ w1, const float* __restrict__ w2,
                                const float* __restrict__ wm,
                                u16* __restrict__ Wh1, u16* __restrict__ Wl1,
                                u16* __restrict__ Wh2, u16* __restrict__ Wl2,
                                u16* __restrict__ Whm, u16* __restrict__ Wlm) {
  int e = blockIdx.x * 256 + threadIdx.x;
  if (e < 27 * 128 * 64) {
    int t = e / (128 * 64), co = (e / 64) % 128, ci = e % 64;
    split2(w1[(co * 64 + ci) * 27 + t], Wh1[e], Wl1[e]);
  }
  if (e < 27 * 128 * 128) {
    int t = e / (128 * 128), co = (e / 128) % 128, ci = e % 128;
    split2(w2[(co * 128 + ci) * 27 + t], Wh2[e], Wl2[e]);
  }
  if (e < 128 * 64) split2(wm[e], Whm[e], Wlm[e]);
}

// ---- K_scatter_mlp: fused scatter + mlp MFMA (PROVEN r13) -----------------
__global__ void __launch_bounds__(256)
scatter_mlp(const float* __restrict__ coords, const float* __restrict__ features,
            const u16* __restrict__ Whm, const u16* __restrict__ Wlm,
            const float* __restrict__ mb,
            float* __restrict__ Gsum, float* __restrict__ Gcnt,
            u16* __restrict__ pf, float* __restrict__ stats) {
  constexpr int TRB = 64 * 65 * 4;          // 16640 B fp32 trans
  constexpr int XSB = 64 * 72 * 2;          // 9216 B bf16 Xs
  constexpr int SBYTES = 4 * 64 * 33 * 4;   // 33792 B epilogue scratch
  constexpr int LBYTES = (TRB + XSB > SBYTES) ? TRB + XSB : SBYTES;
  __shared__ __align__(16) char ldsbuf[LBYTES];
  float (*trans)[65] = (float(*)[65])ldsbuf;
  u16* Xs = (u16*)(ldsbuf + TRB);
  float* ldsW = (float*)ldsbuf;             // aliases; valid after barrier
  __shared__ int vox[64];

  const int tid = threadIdx.x;
  const int wave = tid >> 6, lane = tid & 63;
  const int l15 = lane & 15, q = lane >> 4;
  const int cobase = wave * 32;
  const int bi = blockIdx.x >> 8;
  const int n0 = (blockIdx.x & 255) << 6;

  // calibration (PROVEN r8)
  u16 oneb = f2b(1.0f), lidb = f2b((float)(l15 + 1));
  s16x8 vone, vlid;
#pragma unroll
  for (int e = 0; e < 8; ++e) { vone[e] = (short)oneb; vlid[e] = (short)lidb; }
  f32x4 z4 = {0.f, 0.f, 0.f, 0.f};
  f32x4 d1 = __builtin_amdgcn_mfma_f32_16x16x32_bf16(vlid, vone, z4, 0, 0, 0);
  f32x4 d2 = __builtin_amdgcn_mfma_f32_16x16x32_bf16(vone, vlid, z4, 0, 0, 0);
  int mdec[4], ndec[4];
#pragma unroll
  for (int r = 0; r < 4; ++r) {
    mdec[r] = (int)(d1[r] * 0.03125f + 0.5f) - 1;
    ndec[r] = (int)(d2[r] * 0.03125f + 0.5f) - 1;
  }

  if (tid < 64) {
    const float* cp = coords + ((size_t)bi * NPTS + n0 + tid) * 3;
    int ix = min(max((int)floorf(cp[0] * 32.f), 0), 31);
    int iy = min(max((int)floorf(cp[1] * 32.f), 0), 31);
    int iz = min(max((int)floorf(cp[2] * 32.f), 0), 31);
    vox[tid] = (ix * 32 + iy) * 32 + iz;
  }
  // dual-write staging: one global read feeds both views
  for (int e = tid; e < 4096; e += 256) {
    int ci = e >> 6, nn = e & 63;          // lane varies nn -> coalesced read
    float f = features[((size_t)bi * 64 + ci) * NPTS + n0 + nn];
    trans[nn][ci] = f;
    Xs[nn * 72 + ci] = f2b(f);
  }
  __syncthreads();

  // ---- scatter atomics first (fire-and-forget; drain under MFMA) ----------
  for (int pi = 0; pi < 16; ++pi) {
    int nn = wave * 16 + pi;
    int v = vox[nn];
    atomicAdd(&Gsum[((size_t)bi * R3 + v) * 64 + lane], trans[nn][lane]);
    if (lane == 0) atomicAdd(&Gcnt[bi * R3 + v], 1.f);
  }

  // ---- mlp MFMA (verbatim from proven mlp_mfma) ---------------------------
  f32x4 acc[2][4];  // [ct][vt: 4 point-tiles of 16]
#pragma unroll
  for (int a = 0; a < 2; ++a)
#pragma unroll
    for (int b = 0; b < 4; ++b) acc[a][b] = (f32x4){0.f, 0.f, 0.f, 0.f};

#pragma unroll
  for (int kb = 0; kb < 2; ++kb) {
    const int ko = kb * 32 + q * 8;
    s16x8 ah[2], al[2], bb[4];
#pragma unroll
    for (int ct = 0; ct < 2; ++ct) {
      size_t wo = ((size_t)(cobase + ct * 16 + l15)) * 64 + ko;
      ah[ct] = *(const s16x8*)(Whm + wo);
      al[ct] = *(const s16x8*)(Wlm + wo);
    }
#pragma unroll
    for (int vt = 0; vt < 4; ++vt)
      bb[vt] = *(const s16x8*)(&Xs[(vt * 16 + l15) * 72 + ko]);
#pragma unroll
    for (int ct = 0; ct < 2; ++ct)
#pragma unroll
      for (int vt = 0; vt < 4; ++vt) {
        acc[ct][vt] = __builtin_amdgcn_mfma_f32_16x16x32_bf16(ah[ct], bb[vt], acc[ct][vt], 0, 0, 0);
        acc[ct][vt] = __builtin_amdgcn_mfma_f32_16x16x32_bf16(al[ct], bb[vt], acc[ct][vt], 0, 0, 0);
      }
  }

  // epilogue: decoded scatter -> ldsW[wave][pt][co32], then store + stats
  __syncthreads();   // all trans/Xs reads done -> ldsW may overwrite
#pragma unroll
  for (int ct = 0; ct < 2; ++ct)
#pragma unroll
    for (int vt = 0; vt < 4; ++vt)
#pragma unroll
      for (int r = 0; r < 4; ++r)
        ldsW[(wave * 64 + vt * 16 + ndec[r]) * 33 + ct * 16 + mdec[r]] = acc[ct][vt][r];
  __syncthreads();

  float v[32];
  float s0 = 0.f, q0 = 0.f, s1 = 0.f, q1 = 0.f;
#pragma unroll
  for (int j = 0; j < 32; ++j) {
    v[j] = ldsW[(wave * 64 + lane) * 33 + j] + mb[cobase + j];
    if (j < 16) { s0 += v[j]; q0 = fmaf(v[j], v[j], q0); }
    else        { s1 += v[j]; q1 = fmaf(v[j], v[j], q1); }
  }
  u16 outv[32];
#pragma unroll
  for (int j = 0; j < 32; ++j) outv[j] = f2b(v[j]);
  u16* yp = pf + ((size_t)bi * NPTS + n0 + lane) * 128 + cobase;
#pragma unroll
  for (int k = 0; k < 4; ++k) *(uint4*)(yp + 8 * k) = *(uint4*)(outv + 8 * k);

#pragma unroll
  for (int off = 32; off > 0; off >>= 1) {
    s0 += __shfl_xor(s0, off); q0 += __shfl_xor(q0, off);
    s1 += __shfl_xor(s1, off); q1 += __shfl_xor(q1, off);
  }
  if (lane == 0) {
    atomicAdd(&stats[(bi * 8 + 2 * wave + 0) * 2 + 0], s0);
    atomicAdd(&stats[(bi * 8 + 2 * wave + 0) * 2 + 1], q0);
    atomicAdd(&stats[(bi * 8 + 2 * wave + 1) * 2 + 0], s1);
    atomicAdd(&stats[(bi * 8 + 2 * wave + 1) * 2 + 1], q1);
  }
}

// ---- K_finalize: vectorized (PROVEN r5; standalone is cheaper than fusing
// into conv1's barrier-fenced staging path -- r14 measured +8.5 us net) ----
__global__ void __launch_bounds__(256)
finalize_grid(const float* __restrict__ Gsum, const float* __restrict__ Gcnt,
              u16* __restrict__ X1) {
  size_t g = (size_t)blockIdx.x * 256 + threadIdx.x;  // < 4*32768*16
  float c = fmaxf(Gcnt[g >> 4], 1.f);
  float4 s = ((const float4*)Gsum)[g];
  unsigned h0 = f2b(s.x / c), h1 = f2b(s.y / c), h2 = f2b(s.z / c), h3 = f2b(s.w / c);
  uint2 o; o.x = h0 | (h1 << 16); o.y = h2 | (h3 << 16);
  *(uint2*)(X1 + g * 4) = o;
}

// ---- conv: 3-phase slab staging (EXACT r8-proven kernel, 262 us) ----------
// Stage per-dx a 6-y-line x 34-z slab (204 rows), serve all 9 (dy,dz) taps.
// CLOSED: r1-r4, r6-r7, r9-r12 (9 structural experiments) confirm this is
// the plateau -- MfmaUtil pinned 34-39% across occupancy 12-44%, LDS ratio
// x0.5-x2, both MFMA shapes, three staging schemes, all prefetch variants.
// r14 additionally proved finalize-fusion into staging is net negative.
// 2-term split MFMA + calibrated C/D decode (PROVEN r8/r9).
template<int CIN>
__global__ void __launch_bounds__(256)
conv_mfma_s3(const u16* __restrict__ X, const u16* __restrict__ Wh, const u16* __restrict__ Wl,
             const float* __restrict__ bias, const float* __restrict__ gamma,
             const float* __restrict__ beta, u16* __restrict__ Yb) {
  constexpr int CINP = CIN + 8;            // row stride (odd x 16B)
  constexpr int ROWS = 204;                // 6 y-lines x 34 z (jy=0..5, pz=0..33)
  constexpr int CH8 = CIN / 8;
  constexpr int KS = CIN / 32;
  constexpr int NCH = ROWS * CH8;          // 1632 / 3264 chunks per slab
  constexpr int XBYTES = ROWS * CINP * 2;  // 29376 / 55488
  constexpr int SBYTES = 4 * 2 * 32 * 33 * 4;   // 4 waves x 2 lines x [32co][33z]
  __shared__ __align__(16) char ldsbuf[(XBYTES > SBYTES) ? XBYTES : SBYTES];
  u16* Xs = (u16*)ldsbuf;
  float* ldsW = (float*)ldsbuf;            // valid only after X reads drained

  const int tid = threadIdx.x;
  const int wave = tid >> 6, lane = tid & 63;
  const int l15 = lane & 15, q = lane >> 4;
  const int cobase = wave * 32;

  const int bi = blockIdx.x >> 8;
  const int rem = blockIdx.x & 255;
  const int x = rem >> 3, y0 = (rem & 7) << 2;

  // ---- runtime C/D calibration (PROVEN r8) ----
  u16 oneb = f2b(1.0f), lidb = f2b((float)(l15 + 1));
  s16x8 vone, vlid;
#pragma unroll
  for (int e = 0; e < 8; ++e) { vone[e] = (short)oneb; vlid[e] = (short)lidb; }
  f32x4 z4 = {0.f, 0.f, 0.f, 0.f};
  f32x4 d1 = __builtin_amdgcn_mfma_f32_16x16x32_bf16(vlid, vone, z4, 0, 0, 0);
  f32x4 d2 = __builtin_amdgcn_mfma_f32_16x16x32_bf16(vone, vlid, z4, 0, 0, 0);
  int mdec[4], ndec[4];
#pragma unroll
  for (int r = 0; r < 4; ++r) {
    mdec[r] = (int)(d1[r] * 0.03125f + 0.5f) - 1;
    ndec[r] = (int)(d2[r] * 0.03125f + 0.5f) - 1;
  }

  f32x4 acc[2][2][4];  // [ct][vt][line]
#pragma unroll
  for (int a = 0; a < 2; ++a)
#pragma unroll
    for (int b = 0; b < 2; ++b)
#pragma unroll
      for (int c = 0; c < 4; ++c) acc[a][b][c] = (f32x4){0.f, 0.f, 0.f, 0.f};

  for (int dxs = 0; dxs < 3; ++dxs) {
    __syncthreads();
    const int xs = x + dxs - 1;
    for (int c = tid; c < NCH; c += 256) {   // r0-style bounds-checked staging
      int rr = c / CH8, k = (c % CH8) * 8;
      uint4 val; val.x = val.y = val.z = val.w = 0u;
      int jy = rr / 34;                    // 0..5
      int pz = rr - jy * 34;               // 0..33
      int ys = y0 + jy - 1, zz = pz - 1;
      if (xs >= 0 && xs < 32 && ys >= 0 && ys < 32 && zz >= 0 && zz < 32)
        val = *(const uint4*)(X + ((size_t)bi * R3 + (size_t)((xs * 32 + ys) * 32 + zz)) * CIN + k);
      *(uint4*)(&Xs[rr * CINP + k]) = val;
    }
    __syncthreads();
    for (int dy = 0; dy < 3; ++dy) {       // runtime loop: r0-sized inner body
      const int tb = dxs * 9 + dy * 3;
      const int rbase = dy * 34;
#pragma unroll
      for (int dz = 0; dz < 3; ++dz) {
        const int t = tb + dz;
#pragma unroll
        for (int kb = 0; kb < KS; ++kb) {
          const int ko = kb * 32 + q * 8;
          s16x8 ah[2], al[2], bb[2][4];
#pragma unroll
          for (int ct = 0; ct < 2; ++ct) {
            size_t wo = ((size_t)(t * 128 + cobase + ct * 16 + l15)) * CIN + ko;
            ah[ct] = *(const s16x8*)(Wh + wo);
            al[ct] = *(const s16x8*)(Wl + wo);
          }
#pragma unroll
          for (int vt = 0; vt < 2; ++vt)
#pragma unroll
            for (int ln = 0; ln < 4; ++ln)
              bb[vt][ln] = *(const s16x8*)(
                  &Xs[(rbase + ln * 34 + vt * 16 + l15 + dz) * CINP + ko]);
#pragma unroll
          for (int ct = 0; ct < 2; ++ct)
#pragma unroll
            for (int vt = 0; vt < 2; ++vt)
#pragma unroll
              for (int ln = 0; ln < 4; ++ln) {
                acc[ct][vt][ln] = __builtin_amdgcn_mfma_f32_16x16x32_bf16(
                    ah[ct], bb[vt][ln], acc[ct][vt][ln], 0, 0, 0);
                acc[ct][vt][ln] = __builtin_amdgcn_mfma_f32_16x16x32_bf16(
                    al[ct], bb[vt][ln], acc[ct][vt][ln], 0, 0, 0);
              }
        }
      }
    }
  }

  // ---- epilogue: decoded scatter through LDS, 2 lines per pass (r0) -------
  const int half = lane >> 5, zl = lane & 31;
  for (int p = 0; p < 2; ++p) {
    __syncthreads();   // drains Xs reads -> safe to overwrite
#pragma unroll
    for (int l2 = 0; l2 < 2; ++l2)
#pragma unroll
      for (int ct = 0; ct < 2; ++ct)
#pragma unroll
        for (int vt = 0; vt < 2; ++vt)
#pragma unroll
          for (int r = 0; r < 4; ++r)
            ldsW[((wave * 2 + l2) * 32 + ct * 16 + mdec[r]) * 33 + vt * 16 + ndec[r]] =
                acc[ct][vt][2 * p + l2][r];
    __syncthreads();
    const int co0 = cobase + half * 16;
#pragma unroll
    for (int l2 = 0; l2 < 2; ++l2) {
      float v[16];
#pragma unroll
      for (int j = 0; j < 16; ++j)
        v[j] = ldsW[((wave * 2 + l2) * 32 + half * 16 + j) * 33 + zl] + bias[co0 + j];
      float mu = 0.f;
#pragma unroll
      for (int j = 0; j < 16; ++j) mu += v[j];
      mu *= 0.0625f;
      float var = 0.f;
#pragma unroll
      for (int j = 0; j < 16; ++j) { float d = v[j] - mu; var = fmaf(d, d, var); }
      var *= 0.0625f;
      float rs = rsqrtf(var + 1e-5f);
#pragma unroll
      for (int j = 0; j < 16; ++j) {
        float xn = (v[j] - mu) * rs * gamma[co0 + j] + beta[co0 + j];
        v[j] = silu(xn);
      }
      size_t row = (size_t)bi * R3 + (size_t)((x * 32 + y0 + 2 * p + l2) * 32 + zl);
      u16 outv[16];
#pragma unroll
      for (int j = 0; j < 16; ++j) outv[j] = f2b(v[j]);
      u16* yp = Yb + row * 128 + co0;
      *(uint4*)(yp)     = *(uint4*)(outv);
      *(uint4*)(yp + 8) = *(uint4*)(outv + 8);
    }
  }
}

// ---- K_final (proven) -----------------------------------------------------
__global__ void __launch_bounds__(256)
final_fuse(const float* __restrict__ coords, const u16* __restrict__ H,
           const u16* __restrict__ pf, const float* __restrict__ stats,
           const float* __restrict__ gg, const float* __restrict__ gb,
           float* __restrict__ out) {
  __shared__ float trans[64][130];
  const int tid = threadIdx.x;
  const int wave = tid >> 6, lane = tid & 63;
  const int bi = blockIdx.x >> 8;
  const int p0 = (blockIdx.x & 255) << 6;
  const int co = lane * 2;
  const int grp = co >> 4;
  const float cntInv = 1.f / (16.f * 16384.f);
  float S  = stats[(bi * 8 + grp) * 2 + 0];
  float SS = stats[(bi * 8 + grp) * 2 + 1];
  float mu = S * cntInv;
  float var = SS * cntInv - mu * mu;
  float rs = rsqrtf(var + 1e-5f);
  float g0 = gg[co], g1 = gg[co + 1], b0 = gb[co], b1 = gb[co + 1];

  for (int pi = 0; pi < 16; ++pi) {
    int pl = wave * 16 + pi;
    int p = p0 + pl;
    const float* cp = coords + ((size_t)bi * NPTS + p) * 3;
    float cx = cp[0] * 32.f, cy = cp[1] * 32.f, cz = cp[2] * 32.f;
    float fx = floorf(cx), fy = floorf(cy), fz = floorf(cz);
    int ix = min(max((int)fx, 0), 31);
    int iy = min(max((int)fy, 0), 31);
    int iz = min(max((int)fz, 0), 31);
    float rx = cx - fx, ry = cy - fy, rz = cz - fz;
    int hx = min(ix + 1, 31), hy = min(iy + 1, 31), hz = min(iz + 1, 31);
    float a0 = 0.f, a1 = 0.f;
#pragma unroll
    for (int k = 0; k < 8; ++k) {
      int xb = k >> 2, yb = (k >> 1) & 1, zb = k & 1;
      float w = (xb ? rx : 1.f - rx) * (yb ? ry : 1.f - ry) * (zb ? rz : 1.f - rz);
      int vi = ((xb ? hx : ix) * 32 + (yb ? hy : iy)) * 32 + (zb ? hz : iz);
      unsigned hv = *(const unsigned*)(H + ((size_t)bi * R3 + vi) * 128 + co);
      a0 += w * b2f((u16)(hv & 0xffff));
      a1 += w * b2f((u16)(hv >> 16));
    }
    unsigned pv = *(const unsigned*)(pf + ((size_t)bi * NPTS + p) * 128 + co);
    float q0 = (b2f((u16)(pv & 0xffff)) - mu) * rs * g0 + b0;
    float q1 = (b2f((u16)(pv >> 16)) - mu) * rs * g1 + b1;
    trans[pl][co]     = silu(q0) + a0;
    trans[pl][co + 1] = silu(q1) + a1;
  }
  __syncthreads();
  for (int e = tid; e < 8192; e += 256) {
    int c = e >> 6, pp = e & 63;
    out[((size_t)bi * 128 + c) * NPTS + p0 + pp] = trans[pp][c];
  }
}

// ---- host -----------------------------------------------------------------
extern "C" void kernel_launch(void* const* d_in, const int* in_sizes, int n_in,
                              void* d_out, int out_size, void* d_ws, size_t ws_size,
                              hipStream_t stream) {
  const float* coords   = (const float*)d_in[0];
  const float* features = (const float*)d_in[1];
  const float* conv1_w  = (const float*)d_in[2];
  const float* conv1_b  = (const float*)d_in[3];
  const float* gn1_g    = (const float*)d_in[4];
  const float* gn1_b    = (const float*)d_in[5];
  const float* conv2_w  = (const float*)d_in[6];
  const float* conv2_b  = (const float*)d_in[7];
  const float* gn2_g    = (const float*)d_in[8];
  const float* gn2_b    = (const float*)d_in[9];
  const float* mlp_w    = (const float*)d_in[10];
  const float* mlp_b    = (const float*)d_in[11];
  const float* gnp_g    = (const float*)d_in[12];
  const float* gnp_b    = (const float*)d_in[13];

  char* ws = (char*)d_ws;
  // layout (bytes) -- r13-proven compact layout (~104 MB):
  float* Gsum = (float*)(ws + 0);            // 33554432 fp32 [b][vox][64]; H bf16 aliases after conv1
  u16*   H    = (u16*)(ws + 0);              // 33554432 bf16 [b][vox][128]
  u16*   X1   = (u16*)(ws + 33554432);       // 16777216 bf16 [b][vox][64]  -> 50331648
  u16*   X2   = (u16*)(ws + 50331648);       // 33554432 bf16 [b][vox][128] -> 83886080
  float* Gcnt = (float*)(ws + 83886080);     // 524288   -> 84410368
  float* stats = (float*)(ws + 84410368);    // 4096     -> 84414464
  u16*   pf   = (u16*)(ws + 84676608);       // 16777216 -> 101453824
  u16*   Wh1  = (u16*)(ws + 101453824);      // 442368   -> 101896192
  u16*   Wl1  = (u16*)(ws + 101896192);      // 442368   -> 102338560
  u16*   Wh2  = (u16*)(ws + 102338560);      // 884736   -> 103223296
  u16*   Wl2  = (u16*)(ws + 103223296);      // 884736   -> 104108032
  u16*   Whm  = (u16*)(ws + 104108032);      // 16384    -> 104124416
  u16*   Wlm  = (u16*)(ws + 104124416);      // 16384    -> 104140800 (~104 MB)

  hipMemsetAsync(ws, 0, 33554432, stream);                   // Gsum
  hipMemsetAsync(ws + 83886080, 0, 524288 + 4096, stream);   // Gcnt + stats

  convert_weights<<<(27 * 128 * 128 + 255) / 256, 256, 0, stream>>>(
      conv1_w, conv2_w, mlp_w, Wh1, Wl1, Wh2, Wl2, Whm, Wlm);
  scatter_mlp<<<1024, 256, 0, stream>>>(coords, features, Whm, Wlm, mlp_b,
                                        Gsum, Gcnt, pf, stats);
  finalize_grid<<<8192, 256, 0, stream>>>(Gsum, Gcnt, X1);
  conv_mfma_s3<64><<<1024, 256, 0, stream>>>(
      X1, Wh1, Wl1, conv1_b, gn1_g, gn1_b, X2);
  conv_mfma_s3<128><<<1024, 256, 0, stream>>>(
      X2, Wh2, Wl2, conv2_b, gn2_g, gn2_b, H);
  final_fuse<<<1024, 256, 0, stream>>>(coords, H, pf, stats, gnp_g, gnp_b,
                                       (float*)d_out);
}